// Round 1
// baseline (1284.884 us; speedup 1.0000x reference)
//
#include <hip/hip_runtime.h>
#include <math.h>

// Problem constants (B=1)
#define T_SEQ 4096
#define DMODEL 1024
#define NH 16
#define HD 64           // KD = VD = 64
#define NQT (T_SEQ / 64)

// ---------------------------------------------------------------------------
// Kernel 0: sin/cos table [t][ sin(32) | cos(32) ], double-accurate transcendentals
// of the fp32-rounded angle (matches reference's fp32 t/theta rounding).
// ---------------------------------------------------------------------------
__global__ __launch_bounds__(256)
void sincos_table_kernel(float* __restrict__ tab) {
    int idx = blockIdx.x * 256 + threadIdx.x;
    if (idx >= T_SEQ * 32) return;
    int t = idx >> 5, j = idx & 31;
    double p = (double)((float)j / 31.0f);          // fp32 p like the reference
    float theta = (float)pow(10000.0, p);           // fp32 theta
    float ang = (float)t / theta;                   // fp32 division (ref rounding)
    double a = (double)ang;
    tab[t * 64 + j]      = (float)sin(a);
    tab[t * 64 + 32 + j] = (float)cos(a);
}

// ---------------------------------------------------------------------------
// Kernel 2: RoPE applied in-place to q and k buffers ([h][t][64] layout).
// out[j]    = x[j+32]*cos + x[j]*sin
// out[j+32] = x[j]*cos    - x[j+32]*sin      (j in [0,32))
// ---------------------------------------------------------------------------
__global__ __launch_bounds__(256)
void rope_kernel(float* __restrict__ qk, const float* __restrict__ tab) {
    int idx = blockIdx.x * 256 + threadIdx.x;   // bits: [z:1][h:4][t:12][j:5]
    int j = idx & 31;
    int t = (idx >> 5) & (T_SEQ - 1);
    int h = (idx >> 17) & (NH - 1);
    int z = idx >> 21;                           // 0 = q, 1 = k
    float* base = qk + ((size_t)(z * NH + h) * T_SEQ + t) * HD;
    float s = tab[t * 64 + j];
    float c = tab[t * 64 + 32 + j];
    float a = base[j];
    float b = base[j + 32];
    base[j]      = b * c + a * s;
    base[j + 32] = a * c - b * s;
}

// ---------------------------------------------------------------------------
// Kernels 1 & 4: fp32 GEMM  C[M][N] = A[M][K] . B[N][K]^T + bias[N]
// 128x128 tile, 256 threads, 8x8 per thread (split 4+4 rows/cols),
// k-major LDS tiles -> aligned ds_read_b128 fragments, <=2-way bank aliasing.
// EPI=0: plain store (ldc = N). EPI=1: scatter to q/k/v [h][t][64] buffers.
// ---------------------------------------------------------------------------
template<int EPI>
__global__ __launch_bounds__(256)
void gemm_kernel(const float* __restrict__ A, const float* __restrict__ B,
                 const float* __restrict__ bias, float* __restrict__ out,
                 int M, int N, int K, int ldc) {
    __shared__ float As[16][128];   // [k][m]
    __shared__ float Bs[16][128];   // [k][n]
    const int tid = threadIdx.x;
    const int ty = tid >> 4, tx = tid & 15;
    const int sr = tid >> 2;          // staging row 0..63
    const int kg = (tid & 3) * 4;     // staging k offset 0,4,8,12
    const int row0 = blockIdx.y * 128;
    const int col0 = blockIdx.x * 128;

    const float* Ap = A + (size_t)(row0 + sr) * K + kg;
    const float* Bp = B + (size_t)(col0 + sr) * K + kg;
    const size_t str64 = (size_t)64 * K;

    float acc[8][8];
#pragma unroll
    for (int i = 0; i < 8; ++i)
#pragma unroll
        for (int jj = 0; jj < 8; ++jj) acc[i][jj] = 0.f;

    for (int k0 = 0; k0 < K; k0 += 16) {
        float4 a0 = *(const float4*)(Ap + k0);
        float4 a1 = *(const float4*)(Ap + str64 + k0);
        float4 b0 = *(const float4*)(Bp + k0);
        float4 b1 = *(const float4*)(Bp + str64 + k0);
        __syncthreads();   // previous tile's compute done
        As[kg + 0][sr] = a0.x; As[kg + 1][sr] = a0.y; As[kg + 2][sr] = a0.z; As[kg + 3][sr] = a0.w;
        As[kg + 0][sr + 64] = a1.x; As[kg + 1][sr + 64] = a1.y; As[kg + 2][sr + 64] = a1.z; As[kg + 3][sr + 64] = a1.w;
        Bs[kg + 0][sr] = b0.x; Bs[kg + 1][sr] = b0.y; Bs[kg + 2][sr] = b0.z; Bs[kg + 3][sr] = b0.w;
        Bs[kg + 0][sr + 64] = b1.x; Bs[kg + 1][sr + 64] = b1.y; Bs[kg + 2][sr + 64] = b1.z; Bs[kg + 3][sr + 64] = b1.w;
        __syncthreads();   // tile staged
#pragma unroll
        for (int kk = 0; kk < 16; ++kk) {
            float4 av0 = *(const float4*)&As[kk][ty * 4];
            float4 av1 = *(const float4*)&As[kk][ty * 4 + 64];
            float4 bv0 = *(const float4*)&Bs[kk][tx * 4];
            float4 bv1 = *(const float4*)&Bs[kk][tx * 4 + 64];
            float ar[8] = {av0.x, av0.y, av0.z, av0.w, av1.x, av1.y, av1.z, av1.w};
            float br[8] = {bv0.x, bv0.y, bv0.z, bv0.w, bv1.x, bv1.y, bv1.z, bv1.w};
#pragma unroll
            for (int i = 0; i < 8; ++i)
#pragma unroll
                for (int jj = 0; jj < 8; ++jj)
                    acc[i][jj] = fmaf(ar[i], br[jj], acc[i][jj]);
        }
    }

    if (EPI == 0) {
#pragma unroll
        for (int ih = 0; ih < 2; ++ih)
#pragma unroll
        for (int i = 0; i < 4; ++i) {
            int row = row0 + ih * 64 + ty * 4 + i;
#pragma unroll
            for (int jh = 0; jh < 2; ++jh) {
                int col = col0 + jh * 64 + tx * 4;
                float4 o;
                o.x = acc[ih * 4 + i][jh * 4 + 0] + bias[col + 0];
                o.y = acc[ih * 4 + i][jh * 4 + 1] + bias[col + 1];
                o.z = acc[ih * 4 + i][jh * 4 + 2] + bias[col + 2];
                o.w = acc[ih * 4 + i][jh * 4 + 3] + bias[col + 3];
                *(float4*)(out + (size_t)row * ldc + col) = o;
            }
        }
    } else {
        // qkv scatter. Column block (128 wide) never straddles a 1024-wide buffer.
        float* dst = out + (size_t)(col0 >> 10) * ((size_t)NH * T_SEQ * HD);
        int ncb = col0 & 1023;
#pragma unroll
        for (int jh = 0; jh < 2; ++jh)
#pragma unroll
        for (int jj = 0; jj < 4; ++jj) {
            int nc = ncb + jh * 64 + tx * 4 + jj;
            int hh = nc >> 6, d = nc & 63;
            float bb = bias[col0 + jh * 64 + tx * 4 + jj];
            float* dcol = dst + (size_t)hh * T_SEQ * HD + d;
#pragma unroll
            for (int ih = 0; ih < 2; ++ih)
#pragma unroll
            for (int i = 0; i < 4; ++i) {
                int row = row0 + ih * 64 + ty * 4 + i;
                dcol[(size_t)row * HD] = acc[ih * 4 + i][jh * 4 + jj] + bb;
            }
        }
    }
}

// ---------------------------------------------------------------------------
// Kernel 3: causal flash attention, fp32 vector ALU.
// One block = (head h, 64-query tile qt). 256 threads, 4x4 microkernels.
// S computed TRANSPOSED (S_T[k][q]) so the P store is a float4 with tx as the
// fast dim (bank-spread) and PV reads Ps[kk][ty*4] conflict-free.
// Online softmax: per-q running max in LDS, l kept as per-thread partials.
// ---------------------------------------------------------------------------
__global__ __launch_bounds__(256)
void attn_kernel(const float* __restrict__ qb, const float* __restrict__ kb,
                 const float* __restrict__ vb, float* __restrict__ y) {
    __shared__ float Qs[64][64];   // [d][q], pre-scaled by 1/8
    __shared__ float Ks[64][64];   // [d][k]
    __shared__ float Vs[64][64];   // [k][d]
    __shared__ float Ps[64][64];   // [k][q]
    __shared__ float pm[16][68];   // per-ty partials [part][q] (padded rows)
    __shared__ float m_s[64], scl_s[64], l_s[64];

    const int tid = threadIdx.x;
    const int ty = tid >> 4, tx = tid & 15;
    const int h  = blockIdx.x & (NH - 1);
    const int qt = (NQT - 1) - (blockIdx.x >> 4);   // heavy q-tiles first
    const int q0 = qt * 64;

    const float* qh = qb + (size_t)h * T_SEQ * HD;
    const float* kh = kb + (size_t)h * T_SEQ * HD;
    const float* vh = vb + (size_t)h * T_SEQ * HD;

    const int sr = tid >> 2;          // 0..63
    const int db = (tid & 3) * 16;    // 0,16,32,48

    // stage Q transposed+scaled
#pragma unroll
    for (int c = 0; c < 4; ++c) {
        float4 v = *(const float4*)(qh + (size_t)(q0 + sr) * HD + db + c * 4);
        Qs[db + c * 4 + 0][sr] = v.x * 0.125f;
        Qs[db + c * 4 + 1][sr] = v.y * 0.125f;
        Qs[db + c * 4 + 2][sr] = v.z * 0.125f;
        Qs[db + c * 4 + 3][sr] = v.w * 0.125f;
    }
    if (tid < 64) m_s[tid] = -1e30f;

    float acc[4][4] = {};   // [q'=ty*4+i][d'=tx*4+jj]
    float lp[4] = {};       // l partials for q = tx*4+jj

    for (int kt = 0; kt <= qt; ++kt) {
        const int k0 = kt * 64;
        float4 kr[4], vr[4];
#pragma unroll
        for (int c = 0; c < 4; ++c) {
            kr[c] = *(const float4*)(kh + (size_t)(k0 + sr) * HD + db + c * 4);
            vr[c] = *(const float4*)(vh + (size_t)k0 * HD + c * 1024 + tid * 4);
        }
        __syncthreads();   // previous PV done; safe to overwrite K/V (covers Q stage on iter 0)
#pragma unroll
        for (int c = 0; c < 4; ++c) {
            Ks[db + c * 4 + 0][sr] = kr[c].x;
            Ks[db + c * 4 + 1][sr] = kr[c].y;
            Ks[db + c * 4 + 2][sr] = kr[c].z;
            Ks[db + c * 4 + 3][sr] = kr[c].w;
            *((float4*)Vs + c * 256 + tid) = vr[c];
        }
        __syncthreads();   // tiles staged

        // S_T[k][q]: k = ty*4+i, q = tx*4+jj
        float s[4][4] = {};
#pragma unroll
        for (int dd = 0; dd < 64; ++dd) {
            float4 av = *(const float4*)&Ks[dd][ty * 4];
            float4 bv = *(const float4*)&Qs[dd][tx * 4];
            float ar[4] = {av.x, av.y, av.z, av.w};
            float br[4] = {bv.x, bv.y, bv.z, bv.w};
#pragma unroll
            for (int i = 0; i < 4; ++i)
#pragma unroll
                for (int jj = 0; jj < 4; ++jj)
                    s[i][jj] = fmaf(ar[i], br[jj], s[i][jj]);
        }
        if (kt == qt) {   // causal mask on the diagonal tile
#pragma unroll
            for (int i = 0; i < 4; ++i)
#pragma unroll
                for (int jj = 0; jj < 4; ++jj)
                    if (ty * 4 + i > tx * 4 + jj) s[i][jj] = -1e30f;
        }

        // per-q (column) partial max over this thread's 4 k-rows
        {
            float4 cm;
            cm.x = fmaxf(fmaxf(s[0][0], s[1][0]), fmaxf(s[2][0], s[3][0]));
            cm.y = fmaxf(fmaxf(s[0][1], s[1][1]), fmaxf(s[2][1], s[3][1]));
            cm.z = fmaxf(fmaxf(s[0][2], s[1][2]), fmaxf(s[2][2], s[3][2]));
            cm.w = fmaxf(fmaxf(s[0][3], s[1][3]), fmaxf(s[2][3], s[3][3]));
            *(float4*)&pm[ty][tx * 4] = cm;
        }
        __syncthreads();
        if (tid < 64) {
            float mt = pm[0][tid];
#pragma unroll
            for (int p = 1; p < 16; ++p) mt = fmaxf(mt, pm[p][tid]);
            float mo = m_s[tid];
            float mn = fmaxf(mo, mt);
            m_s[tid] = mn;
            scl_s[tid] = __expf(mo - mn);   // 0 on first tile (mo = -1e30)
        }
        __syncthreads();

        float mcol[4]   = {m_s[tx * 4 + 0], m_s[tx * 4 + 1], m_s[tx * 4 + 2], m_s[tx * 4 + 3]};
        float sclcol[4] = {scl_s[tx * 4 + 0], scl_s[tx * 4 + 1], scl_s[tx * 4 + 2], scl_s[tx * 4 + 3]};
        float sclrow[4] = {scl_s[ty * 4 + 0], scl_s[ty * 4 + 1], scl_s[ty * 4 + 2], scl_s[ty * 4 + 3]};

        float p[4][4];
#pragma unroll
        for (int i = 0; i < 4; ++i) {
#pragma unroll
            for (int jj = 0; jj < 4; ++jj)
                p[i][jj] = __expf(s[i][jj] - mcol[jj]);   // masked -> exp(-1e30) = 0
            float4 pv = make_float4(p[i][0], p[i][1], p[i][2], p[i][3]);
            *(float4*)&Ps[ty * 4 + i][tx * 4] = pv;
        }
#pragma unroll
        for (int jj = 0; jj < 4; ++jj)
            lp[jj] = lp[jj] * sclcol[jj] + (p[0][jj] + p[1][jj] + p[2][jj] + p[3][jj]);
#pragma unroll
        for (int i = 0; i < 4; ++i)
#pragma unroll
            for (int jj = 0; jj < 4; ++jj)
                acc[i][jj] *= sclrow[i];
        __syncthreads();   // Ps ready

        // PV: acc[q][d] += sum_k P_T[k][q] * V[k][d]
#pragma unroll
        for (int kk = 0; kk < 64; ++kk) {
            float4 av = *(const float4*)&Ps[kk][ty * 4];
            float4 bv = *(const float4*)&Vs[kk][tx * 4];
            float ar[4] = {av.x, av.y, av.z, av.w};
            float br[4] = {bv.x, bv.y, bv.z, bv.w};
#pragma unroll
            for (int i = 0; i < 4; ++i)
#pragma unroll
                for (int jj = 0; jj < 4; ++jj)
                    acc[i][jj] = fmaf(ar[i], br[jj], acc[i][jj]);
        }
    }

    // final l reduction (reuse pm)
    __syncthreads();
    *(float4*)&pm[ty][tx * 4] = make_float4(lp[0], lp[1], lp[2], lp[3]);
    __syncthreads();
    if (tid < 64) {
        float ssum = 0.f;
#pragma unroll
        for (int p = 0; p < 16; ++p) ssum += pm[p][tid];
        l_s[tid] = ssum;
    }
    __syncthreads();

    float inv[4] = {1.f / l_s[ty * 4 + 0], 1.f / l_s[ty * 4 + 1],
                    1.f / l_s[ty * 4 + 2], 1.f / l_s[ty * 4 + 3]};
#pragma unroll
    for (int i = 0; i < 4; ++i) {
        float4 o = make_float4(acc[i][0] * inv[i], acc[i][1] * inv[i],
                               acc[i][2] * inv[i], acc[i][3] * inv[i]);
        *(float4*)(y + (size_t)(q0 + ty * 4 + i) * DMODEL + h * HD + tx * 4) = o;
    }
}

// ---------------------------------------------------------------------------
extern "C" void kernel_launch(void* const* d_in, const int* in_sizes, int n_in,
                              void* d_out, int out_size, void* d_ws, size_t ws_size,
                              hipStream_t stream) {
    const float* x     = (const float*)d_in[0];   // [1][4096][1024]
    const float* W_in  = (const float*)d_in[1];   // [3072][1024]
    const float* b_in  = (const float*)d_in[2];   // [3072]
    const float* W_out = (const float*)d_in[3];   // [1024][1024]
    const float* b_out = (const float*)d_in[4];   // [1024]
    float* out = (float*)d_out;                   // [4096][1024]

    float* ws = (float*)d_ws;
    const size_t HTD = (size_t)NH * T_SEQ * HD;   // 4,194,304 floats
    float* q_ws = ws;                 // [h][t][64]
    float* k_ws = ws + HTD;
    float* v_ws = ws + 2 * HTD;
    float* y_ws = ws + 3 * HTD;       // [t][1024]
    float* tab  = ws + 4 * HTD;       // [t][64] sin|cos

    // 0) sin/cos table
    sincos_table_kernel<<<(T_SEQ * 32 + 255) / 256, 256, 0, stream>>>(tab);

    // 1) proj GEMM + qkv scatter: [4096]x[3072] from K=1024
    gemm_kernel<1><<<dim3(3072 / 128, T_SEQ / 128), 256, 0, stream>>>(
        x, W_in, b_in, q_ws, T_SEQ, 3 * NH * HD, DMODEL, 0);

    // 2) RoPE in-place on q and k
    rope_kernel<<<(2 * NH * T_SEQ * 32) / 256, 256, 0, stream>>>(q_ws, tab);

    // 3) causal flash attention -> y_ws [t][h*64+d]
    attn_kernel<<<NQT * NH, 256, 0, stream>>>(q_ws, k_ws, v_ws, y_ws);

    // 4) out GEMM: y . W_out^T + b_out
    gemm_kernel<0><<<dim3(DMODEL / 128, T_SEQ / 128), 256, 0, stream>>>(
        y_ws, W_out, b_out, out, T_SEQ, DMODEL, DMODEL, DMODEL);
}

// Round 3
// 660.227 us; speedup vs baseline: 1.9461x; 1.9461x over previous
//
#include <hip/hip_runtime.h>
#include <math.h>

// Problem constants (B=1)
#define T_SEQ 4096
#define DMODEL 1024
#define NH 16
#define HD 64           // KD = VD = 64
#define NQT (T_SEQ / 64)

typedef _Float16 f16x4 __attribute__((ext_vector_type(4)));
typedef _Float16 f16x8 __attribute__((ext_vector_type(8)));
typedef float f32x4 __attribute__((ext_vector_type(4)));

// ---------------------------------------------------------------------------
// Kernel 0: sin/cos table [t][ sin(32) | cos(32) ]
// ---------------------------------------------------------------------------
__global__ __launch_bounds__(256)
void sincos_table_kernel(float* __restrict__ tab) {
    int idx = blockIdx.x * 256 + threadIdx.x;
    if (idx >= T_SEQ * 32) return;
    int t = idx >> 5, j = idx & 31;
    double p = (double)((float)j / 31.0f);
    float theta = (float)pow(10000.0, p);
    float ang = (float)t / theta;
    double a = (double)ang;
    tab[t * 64 + j]      = (float)sin(a);
    tab[t * 64 + 32 + j] = (float)cos(a);
}

// ---------------------------------------------------------------------------
// Kernel 2: RoPE in-place on q and k buffers ([h][t][64] layout).
// ---------------------------------------------------------------------------
__global__ __launch_bounds__(256)
void rope_kernel(float* __restrict__ qk, const float* __restrict__ tab) {
    int idx = blockIdx.x * 256 + threadIdx.x;   // bits: [z:1][h:4][t:12][j:5]
    int j = idx & 31;
    int t = (idx >> 5) & (T_SEQ - 1);
    int h = (idx >> 17) & (NH - 1);
    int z = idx >> 21;                           // 0 = q, 1 = k
    float* base = qk + ((size_t)(z * NH + h) * T_SEQ + t) * HD;
    float s = tab[t * 64 + j];
    float c = tab[t * 64 + 32 + j];
    float a = base[j];
    float b = base[j + 32];
    base[j]      = b * c + a * s;
    base[j + 32] = a * c - b * s;
}

// ---------------------------------------------------------------------------
// Kernel 2.5: cast roped K [h][t][64] and transposed V [h][d][t] to f16.
// ---------------------------------------------------------------------------
__global__ __launch_bounds__(256)
void cast_kv_kernel(const float* __restrict__ k_ws, const float* __restrict__ vt_ws,
                    _Float16* __restrict__ k16, _Float16* __restrict__ v16t) {
    const size_t N8 = (size_t)NH * T_SEQ * HD / 8;   // 524288 vec8 per tensor
    size_t gid = (size_t)blockIdx.x * 256 + threadIdx.x;
    const float* src; _Float16* dst; size_t i = gid;
    if (gid < N8) { src = k_ws; dst = k16; }
    else         { src = vt_ws; dst = v16t; i = gid - N8; }
    float4 a = *((const float4*)src + i * 2);
    float4 b = *((const float4*)src + i * 2 + 1);
    f16x8 o = {(_Float16)a.x, (_Float16)a.y, (_Float16)a.z, (_Float16)a.w,
               (_Float16)b.x, (_Float16)b.y, (_Float16)b.z, (_Float16)b.w};
    *((f16x8*)dst + i) = o;
}

// ---------------------------------------------------------------------------
// Kernels 1 & 4: fp32 GEMM  C[M][N] = A[M][K] . B[N][K]^T + bias[N]
// EPI=0: plain store (ldc = N). EPI=1: scatter q/k -> [h][t][64], v -> [h][d][t].
// ---------------------------------------------------------------------------
template<int EPI>
__global__ __launch_bounds__(256)
void gemm_kernel(const float* __restrict__ A, const float* __restrict__ B,
                 const float* __restrict__ bias, float* __restrict__ out,
                 int M, int N, int K, int ldc) {
    __shared__ float As[16][128];   // [k][m]
    __shared__ float Bs[16][128];   // [k][n]
    const int tid = threadIdx.x;
    const int ty = tid >> 4, tx = tid & 15;
    const int sr = tid >> 2;
    const int kg = (tid & 3) * 4;
    const int row0 = blockIdx.y * 128;
    const int col0 = blockIdx.x * 128;

    const float* Ap = A + (size_t)(row0 + sr) * K + kg;
    const float* Bp = B + (size_t)(col0 + sr) * K + kg;
    const size_t str64 = (size_t)64 * K;

    float acc[8][8];
#pragma unroll
    for (int i = 0; i < 8; ++i)
#pragma unroll
        for (int jj = 0; jj < 8; ++jj) acc[i][jj] = 0.f;

    for (int k0 = 0; k0 < K; k0 += 16) {
        float4 a0 = *(const float4*)(Ap + k0);
        float4 a1 = *(const float4*)(Ap + str64 + k0);
        float4 b0 = *(const float4*)(Bp + k0);
        float4 b1 = *(const float4*)(Bp + str64 + k0);
        __syncthreads();
        As[kg + 0][sr] = a0.x; As[kg + 1][sr] = a0.y; As[kg + 2][sr] = a0.z; As[kg + 3][sr] = a0.w;
        As[kg + 0][sr + 64] = a1.x; As[kg + 1][sr + 64] = a1.y; As[kg + 2][sr + 64] = a1.z; As[kg + 3][sr + 64] = a1.w;
        Bs[kg + 0][sr] = b0.x; Bs[kg + 1][sr] = b0.y; Bs[kg + 2][sr] = b0.z; Bs[kg + 3][sr] = b0.w;
        Bs[kg + 0][sr + 64] = b1.x; Bs[kg + 1][sr + 64] = b1.y; Bs[kg + 2][sr + 64] = b1.z; Bs[kg + 3][sr + 64] = b1.w;
        __syncthreads();
#pragma unroll
        for (int kk = 0; kk < 16; ++kk) {
            float4 av0 = *(const float4*)&As[kk][ty * 4];
            float4 av1 = *(const float4*)&As[kk][ty * 4 + 64];
            float4 bv0 = *(const float4*)&Bs[kk][tx * 4];
            float4 bv1 = *(const float4*)&Bs[kk][tx * 4 + 64];
            float ar[8] = {av0.x, av0.y, av0.z, av0.w, av1.x, av1.y, av1.z, av1.w};
            float br[8] = {bv0.x, bv0.y, bv0.z, bv0.w, bv1.x, bv1.y, bv1.z, bv1.w};
#pragma unroll
            for (int i = 0; i < 8; ++i)
#pragma unroll
                for (int jj = 0; jj < 8; ++jj)
                    acc[i][jj] = fmaf(ar[i], br[jj], acc[i][jj]);
        }
    }

    if (EPI == 0) {
#pragma unroll
        for (int ih = 0; ih < 2; ++ih)
#pragma unroll
        for (int i = 0; i < 4; ++i) {
            int row = row0 + ih * 64 + ty * 4 + i;
#pragma unroll
            for (int jh = 0; jh < 2; ++jh) {
                int col = col0 + jh * 64 + tx * 4;
                float4 o;
                o.x = acc[ih * 4 + i][jh * 4 + 0] + bias[col + 0];
                o.y = acc[ih * 4 + i][jh * 4 + 1] + bias[col + 1];
                o.z = acc[ih * 4 + i][jh * 4 + 2] + bias[col + 2];
                o.w = acc[ih * 4 + i][jh * 4 + 3] + bias[col + 3];
                *(float4*)(out + (size_t)row * ldc + col) = o;
            }
        }
    } else {
        const size_t HTD = (size_t)NH * T_SEQ * HD;
        int tensor = col0 >> 10;                  // 0=q, 1=k, 2=v
        int ncb = col0 & 1023;
#pragma unroll
        for (int jh = 0; jh < 2; ++jh) {
            int nc = ncb + jh * 64 + tx * 4;      // 4 consecutive cols, same head
            int hh = nc >> 6, d = nc & 63;
            float4 bb = *(const float4*)(bias + col0 + jh * 64 + tx * 4);
            if (tensor < 2) {
                // q/k: [h][t][64], float4 along d
                float* dst = out + (size_t)tensor * HTD + ((size_t)hh * T_SEQ) * HD + d;
#pragma unroll
                for (int ih = 0; ih < 2; ++ih)
#pragma unroll
                for (int i = 0; i < 4; ++i) {
                    int row = row0 + ih * 64 + ty * 4 + i;
                    float4 o;
                    o.x = acc[ih * 4 + i][jh * 4 + 0] + bb.x;
                    o.y = acc[ih * 4 + i][jh * 4 + 1] + bb.y;
                    o.z = acc[ih * 4 + i][jh * 4 + 2] + bb.z;
                    o.w = acc[ih * 4 + i][jh * 4 + 3] + bb.w;
                    *(float4*)(dst + (size_t)row * HD) = o;
                }
            } else {
                // v transposed: [h][d][t], float4 along t (rows)
                float bj[4] = {bb.x, bb.y, bb.z, bb.w};
#pragma unroll
                for (int jj = 0; jj < 4; ++jj) {
                    float* dv = out + 2 * HTD + ((size_t)hh * HD + d + jj) * T_SEQ;
#pragma unroll
                    for (int ih = 0; ih < 2; ++ih) {
                        int row = row0 + ih * 64 + ty * 4;
                        float4 o;
                        o.x = acc[ih * 4 + 0][jh * 4 + jj] + bj[jj];
                        o.y = acc[ih * 4 + 1][jh * 4 + jj] + bj[jj];
                        o.z = acc[ih * 4 + 2][jh * 4 + jj] + bj[jj];
                        o.w = acc[ih * 4 + 3][jh * 4 + jj] + bj[jj];
                        *(float4*)(dv + row) = o;
                    }
                }
            }
        }
    }
}

// ---------------------------------------------------------------------------
// Kernel 3: causal flash attention with f16 MFMA (16x16x32), fp32 softmax/accum.
// Block = 4 waves; wave w owns 16 q rows. KV tile = 64 keys shared via LDS.
// Swapped QK^T: S^T = mfma(K, Q) -> lane holds S^T[key][q=lane&15]; softmax is
// in-lane + shfl_xor(16,32). P^T stored per-wave as [kg][q][8] f16, read back
// as the PV B-fragment. PV: O^T = mfma(V^T, P^T). K/V LDS rows XOR-swizzled.
// ---------------------------------------------------------------------------
__global__ __launch_bounds__(256)
void attn_kernel(const float* __restrict__ qb, const _Float16* __restrict__ k16,
                 const _Float16* __restrict__ v16t, float* __restrict__ y) {
    __shared__ _Float16 Klds[64 * 64];     // [key][d], swizzled
    __shared__ _Float16 Vlds[64 * 64];     // [d][key], swizzled
    __shared__ _Float16 Plds[4 * 16 * 64]; // per-wave [kg(8)][q(16)][8]

    const int tid  = threadIdx.x;
    const int w    = tid >> 6;
    const int lane = tid & 63;
    const int lq   = lane & 15;
    const int lg   = lane >> 4;

    const int bid = blockIdx.x;
    const int h   = ((bid & 7) << 1) | ((bid >> 3) & 1);  // head -> XCD affinity
    const int qt  = (NQT - 1) - (bid >> 4);               // heavy q-tiles first
    const int q0  = qt * 64;

    const float*    qh = qb   + (size_t)h * T_SEQ * HD;
    const _Float16* kh = k16  + (size_t)h * T_SEQ * HD;
    const _Float16* vh = v16t + (size_t)h * HD * T_SEQ;

    // Q fragments (B-operand): qf[ks][i] = Q[q0+w*16+lq][lg*8+ks*32+i] * 0.125
    const int qrow = q0 + w * 16 + lq;
    f16x8 qf[2];
#pragma unroll
    for (int ks = 0; ks < 2; ++ks) {
        float4 a = *(const float4*)(qh + (size_t)qrow * HD + lg * 8 + ks * 32);
        float4 b = *(const float4*)(qh + (size_t)qrow * HD + lg * 8 + ks * 32 + 4);
        f16x8 t = {(_Float16)(a.x * 0.125f), (_Float16)(a.y * 0.125f),
                   (_Float16)(a.z * 0.125f), (_Float16)(a.w * 0.125f),
                   (_Float16)(b.x * 0.125f), (_Float16)(b.y * 0.125f),
                   (_Float16)(b.z * 0.125f), (_Float16)(b.w * 0.125f)};
        qf[ks] = t;
    }

    const int srow = tid >> 4;           // staging row (+16 per it)
    const int scol = (tid & 15) * 4;     // staging f16 col
    const int schk = (tid & 15) >> 1;    // 16B chunk within row
    const int ssub = (tid & 1) * 8;      // byte offset within chunk

    float m_r = -3e38f, l_r = 0.f;
    f32x4 acco[4] = {};                  // O^T accum: d-block mb, col q=lq

    _Float16* Pw = Plds + w * 1024;

    for (int kt = 0; kt <= qt; ++kt) {
        const int k0 = kt * 64;
        f16x4 kreg[4], vreg[4];
#pragma unroll
        for (int it = 0; it < 4; ++it) {
            int row = srow + it * 16;
            kreg[it] = *(const f16x4*)(kh + (size_t)(k0 + row) * HD + scol);
            vreg[it] = *(const f16x4*)(vh + (size_t)row * T_SEQ + k0 + scol);
        }
        __syncthreads();   // all waves done reading previous K/V tiles
#pragma unroll
        for (int it = 0; it < 4; ++it) {
            int row = srow + it * 16;
            int chunk = schk ^ (row & 7);
            *(f16x4*)((char*)Klds + row * 128 + chunk * 16 + ssub) = kreg[it];
            *(f16x4*)((char*)Vlds + row * 128 + chunk * 16 + ssub) = vreg[it];
        }
        __syncthreads();   // tiles staged

        // QK^T: S^T[key][q], key-blocks mb
        f32x4 s[4] = {};
#pragma unroll
        for (int mb = 0; mb < 4; ++mb) {
            int row = mb * 16 + lq;
#pragma unroll
            for (int ks = 0; ks < 2; ++ks) {
                f16x8 kf = *(const f16x8*)((char*)Klds + row * 128 +
                                           (((lg + 4 * ks) ^ (lq & 7)) * 16));
                s[mb] = __builtin_amdgcn_mfma_f32_16x16x32_f16(kf, qf[ks], s[mb], 0, 0, 0);
            }
        }
        if (kt == qt) {   // causal mask on diagonal tile
            const int qloc = w * 16 + lq;
#pragma unroll
            for (int mb = 0; mb < 4; ++mb)
#pragma unroll
                for (int r = 0; r < 4; ++r)
                    if (mb * 16 + lg * 4 + r > qloc) s[mb][r] = -3e38f;
        }

        // online softmax (per-lane q = lq; reduce over keys via lg lanes)
        float tmax = s[0][0];
#pragma unroll
        for (int mb = 0; mb < 4; ++mb)
#pragma unroll
            for (int r = 0; r < 4; ++r) tmax = fmaxf(tmax, s[mb][r]);
        tmax = fmaxf(tmax, __shfl_xor(tmax, 16));
        tmax = fmaxf(tmax, __shfl_xor(tmax, 32));
        float mn  = fmaxf(m_r, tmax);
        float scl = __expf(m_r - mn);
        m_r = mn;

        float tsum = 0.f;
#pragma unroll
        for (int mb = 0; mb < 4; ++mb) {
            float p0 = __expf(s[mb][0] - mn), p1 = __expf(s[mb][1] - mn);
            float p2 = __expf(s[mb][2] - mn), p3 = __expf(s[mb][3] - mn);
            tsum += (p0 + p1) + (p2 + p3);
            f16x4 pk = {(_Float16)p0, (_Float16)p1, (_Float16)p2, (_Float16)p3};
            // keys mb*16+lg*4 .. +3 for q=lq -> [kg][q][8] layout
            *(f16x4*)(Pw + (mb * 2 + (lg >> 1)) * 128 + lq * 8 + (lg & 1) * 4) = pk;
        }
        tsum += __shfl_xor(tsum, 16);
        tsum += __shfl_xor(tsum, 32);
        l_r = l_r * scl + tsum;
#pragma unroll
        for (int mb = 0; mb < 4; ++mb)
#pragma unroll
            for (int r = 0; r < 4; ++r) acco[mb][r] *= scl;

        // PV: O^T[d][q] += V^T[d][key] . P^T[key][q]
        f16x8 pf[2];
#pragma unroll
        for (int ks = 0; ks < 2; ++ks)
            pf[ks] = *(const f16x8*)(Pw + (lg + 4 * ks) * 128 + lq * 8);
#pragma unroll
        for (int mb = 0; mb < 4; ++mb) {
            int row = mb * 16 + lq;
#pragma unroll
            for (int ks = 0; ks < 2; ++ks) {
                f16x8 vf = *(const f16x8*)((char*)Vlds + row * 128 +
                                           (((lg + 4 * ks) ^ (lq & 7)) * 16));
                acco[mb] = __builtin_amdgcn_mfma_f32_16x16x32_f16(vf, pf[ks], acco[mb], 0, 0, 0);
            }
        }
    }

    // epilogue: O[q][d] = O^T / l
    float inv = 1.f / l_r;
#pragma unroll
    for (int mb = 0; mb < 4; ++mb) {
        float4 o = make_float4(acco[mb][0] * inv, acco[mb][1] * inv,
                               acco[mb][2] * inv, acco[mb][3] * inv);
        *(float4*)(y + (size_t)qrow * DMODEL + h * HD + mb * 16 + lg * 4) = o;
    }
}

// ---------------------------------------------------------------------------
extern "C" void kernel_launch(void* const* d_in, const int* in_sizes, int n_in,
                              void* d_out, int out_size, void* d_ws, size_t ws_size,
                              hipStream_t stream) {
    const float* x     = (const float*)d_in[0];
    const float* W_in  = (const float*)d_in[1];
    const float* b_in  = (const float*)d_in[2];
    const float* W_out = (const float*)d_in[3];
    const float* b_out = (const float*)d_in[4];
    float* out = (float*)d_out;

    float* ws = (float*)d_ws;
    const size_t HTD = (size_t)NH * T_SEQ * HD;   // 4,194,304
    float* q_ws  = ws;                   // [h][t][64] f32
    float* k_ws  = ws + HTD;             // [h][t][64] f32
    float* vt_ws = ws + 2 * HTD;         // [h][d][t] f32 (transposed)
    float* y_ws  = ws + 3 * HTD;         // [t][1024] f32
    float* tab   = ws + 4 * HTD;         // [t][64] sin|cos
    _Float16* k16  = (_Float16*)(ws + 4 * HTD + (size_t)T_SEQ * 64);
    _Float16* v16t = k16 + HTD;

    // 0) sin/cos table
    sincos_table_kernel<<<(T_SEQ * 32 + 255) / 256, 256, 0, stream>>>(tab);

    // 1) proj GEMM + qkv scatter (v transposed)
    gemm_kernel<1><<<dim3(3072 / 128, T_SEQ / 128), 256, 0, stream>>>(
        x, W_in, b_in, q_ws, T_SEQ, 3 * NH * HD, DMODEL, 0);

    // 2) RoPE in-place on q and k
    rope_kernel<<<(2 * NH * T_SEQ * 32) / 256, 256, 0, stream>>>(q_ws, tab);

    // 2.5) cast roped K and transposed V to f16
    cast_kv_kernel<<<(2 * HTD / 8 + 255) / 256, 256, 0, stream>>>(k_ws, vt_ws, k16, v16t);

    // 3) causal flash attention (f16 MFMA) -> y_ws [t][h*64+d]
    attn_kernel<<<NQT * NH, 256, 0, stream>>>(q_ws, k16, v16t, y_ws);

    // 4) out GEMM
    gemm_kernel<0><<<dim3(DMODEL / 128, T_SEQ / 128), 256, 0, stream>>>(
        y_ws, W_out, b_out, out, T_SEQ, DMODEL, DMODEL, DMODEL);
}

// Round 4
// 238.881 us; speedup vs baseline: 5.3788x; 2.7638x over previous
//
#include <hip/hip_runtime.h>
#include <math.h>

// Problem constants (B=1)
#define T_SEQ 4096
#define DMODEL 1024
#define NH 16
#define HD 64           // KD = VD = 64
#define NQT (T_SEQ / 64)

typedef _Float16 f16x4 __attribute__((ext_vector_type(4)));
typedef _Float16 f16x8 __attribute__((ext_vector_type(8)));
typedef float f32x4 __attribute__((ext_vector_type(4)));

#define HTD ((size_t)NH * T_SEQ * HD)   // 4,194,304

// ---------------------------------------------------------------------------
// Kernel 0: sin/cos table [t][ sin(32) | cos(32) ]
// ---------------------------------------------------------------------------
__global__ __launch_bounds__(256)
void sincos_table_kernel(float* __restrict__ tab) {
    int idx = blockIdx.x * 256 + threadIdx.x;
    if (idx >= T_SEQ * 32) return;
    int t = idx >> 5, j = idx & 31;
    double p = (double)((float)j / 31.0f);
    float theta = (float)pow(10000.0, p);
    float ang = (float)t / theta;
    double a = (double)ang;
    tab[t * 64 + j]      = (float)sin(a);
    tab[t * 64 + 32 + j] = (float)cos(a);
}

// ---------------------------------------------------------------------------
// Kernel 0.5: cast x, W_in, W_out to f16 (vec8).
// ---------------------------------------------------------------------------
__global__ __launch_bounds__(256)
void cast3_kernel(const float* __restrict__ x, const float* __restrict__ wi,
                  const float* __restrict__ wo, _Float16* __restrict__ x16,
                  _Float16* __restrict__ wi16, _Float16* __restrict__ wo16) {
    size_t gid = (size_t)blockIdx.x * 256 + threadIdx.x;   // 1,048,576 total
    const float* src; _Float16* dst; size_t i;
    if (gid < 524288)       { src = x;  dst = x16;  i = gid; }
    else if (gid < 917504)  { src = wi; dst = wi16; i = gid - 524288; }
    else                    { src = wo; dst = wo16; i = gid - 917504; }
    float4 a = *((const float4*)src + i * 2);
    float4 b = *((const float4*)src + i * 2 + 1);
    f16x8 o = {(_Float16)a.x, (_Float16)a.y, (_Float16)a.z, (_Float16)a.w,
               (_Float16)b.x, (_Float16)b.y, (_Float16)b.z, (_Float16)b.w};
    *((f16x8*)dst + i) = o;
}

// ---------------------------------------------------------------------------
// Kernel 2: RoPE. q: f32 in-place. k: f32 -> k16 (f16).
// ---------------------------------------------------------------------------
__global__ __launch_bounds__(256)
void rope_kernel(float* __restrict__ q, const float* __restrict__ k,
                 _Float16* __restrict__ k16, const float* __restrict__ tab) {
    int idx = blockIdx.x * 256 + threadIdx.x;   // bits: [z:1][h:4][t:12][j:5]
    int j = idx & 31;
    int t = (idx >> 5) & (T_SEQ - 1);
    int h = (idx >> 17) & (NH - 1);
    int z = idx >> 21;                           // 0 = q, 1 = k
    float s = tab[t * 64 + j];
    float c = tab[t * 64 + 32 + j];
    size_t off = ((size_t)h * T_SEQ + t) * HD;
    if (z == 0) {
        float* base = q + off;
        float a = base[j], b = base[j + 32];
        base[j]      = b * c + a * s;
        base[j + 32] = a * c - b * s;
    } else {
        const float* base = k + off;
        float a = base[j], b = base[j + 32];
        k16[off + j]      = (_Float16)(b * c + a * s);
        k16[off + j + 32] = (_Float16)(a * c - b * s);
    }
}

// ---------------------------------------------------------------------------
// Kernels 1 & 4: f16 MFMA GEMM  C[M][N] = A[M][K] . B[N][K]^T + bias[N]
// 128x128 tile, BK=64, 4 waves (2x2 of 64x64), mfma_f32_16x16x32_f16.
// LDS rows are 128 B -> XOR swizzle chunk^(row&7): fragment ds_read_b128 is
// 2-way (free), staging writes at the 8-lane floor. Next K-tile's global
// loads issue between the staging barrier and compute (latency hidden).
// EPI=0: f32 out [M][N]. EPI=1: q/k f32 [h][t][64] (rope next), v f16 [h][d][t].
// ---------------------------------------------------------------------------
template<int EPI>
__global__ __launch_bounds__(256)
void gemm16_kernel(const _Float16* __restrict__ A, const _Float16* __restrict__ B,
                   const float* __restrict__ bias, float* __restrict__ out,
                   _Float16* __restrict__ outv, int M, int N, int K, int gx) {
    __shared__ _Float16 Alds[128 * 64];
    __shared__ _Float16 Blds[128 * 64];
    const int tid = threadIdx.x;
    const int w = tid >> 6, lane = tid & 63, lq = lane & 15, lg = lane >> 4;
    const int wr = w >> 1, wc = w & 1;

    // bijective XCD swizzle (gridDim.x % 8 == 0 for both call sites)
    int cpx = (int)gridDim.x >> 3;
    int tileid = (blockIdx.x & 7) * cpx + (blockIdx.x >> 3);
    const int bx = tileid % gx, by = tileid / gx;
    const int row0 = by * 128, col0 = bx * 128;

    const int ra = tid >> 1, ha = tid & 1;
    const _Float16* Ap = A + (size_t)(row0 + ra) * K + ha * 32;
    const _Float16* Bp = B + (size_t)(col0 + ra) * K + ha * 32;
    char* Awr = (char*)Alds + ra * 128;
    char* Bwr = (char*)Blds + ra * 128;
    int wsw[4];
#pragma unroll
    for (int j = 0; j < 4; ++j) wsw[j] = ((ha * 4 + j) ^ (ra & 7)) * 16;

    f32x4 acc[4][4] = {};
    f16x8 sa[4], sb[4];
#pragma unroll
    for (int j = 0; j < 4; ++j) {
        sa[j] = *(const f16x8*)(Ap + j * 8);
        sb[j] = *(const f16x8*)(Bp + j * 8);
    }

    const int nkt = K >> 6;
    for (int kt = 0; kt < nkt; ++kt) {
        __syncthreads();   // previous compute done reading LDS
#pragma unroll
        for (int j = 0; j < 4; ++j) {
            *(f16x8*)(Awr + wsw[j]) = sa[j];
            *(f16x8*)(Bwr + wsw[j]) = sb[j];
        }
        __syncthreads();   // staged
        if (kt + 1 < nkt) {
            int kn = (kt + 1) << 6;
#pragma unroll
            for (int j = 0; j < 4; ++j) {
                sa[j] = *(const f16x8*)(Ap + kn + j * 8);
                sb[j] = *(const f16x8*)(Bp + kn + j * 8);
            }
        }
#pragma unroll
        for (int ks = 0; ks < 2; ++ks) {
            f16x8 af[4], bf[4];
            const int cofs = ((ks * 4 + lg) ^ (lq & 7)) * 16;
#pragma unroll
            for (int i = 0; i < 4; ++i) {
                int rA = wr * 64 + i * 16 + lq;
                int rB = wc * 64 + i * 16 + lq;
                af[i] = *(const f16x8*)((char*)Alds + rA * 128 + cofs);
                bf[i] = *(const f16x8*)((char*)Blds + rB * 128 + cofs);
            }
#pragma unroll
            for (int mi = 0; mi < 4; ++mi)
#pragma unroll
                for (int nj = 0; nj < 4; ++nj)
                    acc[mi][nj] = __builtin_amdgcn_mfma_f32_16x16x32_f16(
                        af[mi], bf[nj], acc[mi][nj], 0, 0, 0);
        }
    }

    // epilogue. D-layout: C[row0+wr*64+mi*16+lg*4+r][col0+wc*64+nj*16+lq]
    if (EPI == 0) {
#pragma unroll
        for (int nj = 0; nj < 4; ++nj) {
            int n = col0 + wc * 64 + nj * 16 + lq;
            float bv = bias[n];
#pragma unroll
            for (int mi = 0; mi < 4; ++mi) {
                int t0 = row0 + wr * 64 + mi * 16 + lg * 4;
#pragma unroll
                for (int r = 0; r < 4; ++r)
                    out[(size_t)(t0 + r) * N + n] = acc[mi][nj][r] + bv;
            }
        }
    } else {
        const int tensor = col0 >> 10;            // 0=q, 1=k, 2=v (no straddle)
        const int m0b = row0 + wr * 64;
        if (tensor == 2) {
            // v: f16 transposed [h][d][t], f16x4 along t
#pragma unroll
            for (int nj = 0; nj < 4; ++nj) {
                int n = col0 + wc * 64 + nj * 16 + lq;
                int nn = n & 1023; int hh = nn >> 6, d = nn & 63;
                float bv = bias[n];
                _Float16* dv = outv + (size_t)(hh * 64 + d) * T_SEQ;
#pragma unroll
                for (int mi = 0; mi < 4; ++mi) {
                    int t0 = m0b + mi * 16 + lg * 4;
                    f16x4 val = {(_Float16)(acc[mi][nj][0] + bv),
                                 (_Float16)(acc[mi][nj][1] + bv),
                                 (_Float16)(acc[mi][nj][2] + bv),
                                 (_Float16)(acc[mi][nj][3] + bv)};
                    *(f16x4*)(dv + t0) = val;
                }
            }
        } else {
            // q/k: f32 [h][t][64]
            float* dst = out + (size_t)tensor * HTD;
#pragma unroll
            for (int nj = 0; nj < 4; ++nj) {
                int n = col0 + wc * 64 + nj * 16 + lq;
                int nn = n & 1023; int hh = nn >> 6, d = nn & 63;
                float bv = bias[n];
                float* dcol = dst + (size_t)hh * T_SEQ * HD + d;
#pragma unroll
                for (int mi = 0; mi < 4; ++mi) {
                    int t0 = m0b + mi * 16 + lg * 4;
#pragma unroll
                    for (int r = 0; r < 4; ++r)
                        dcol[(size_t)(t0 + r) * HD] = acc[mi][nj][r] + bv;
                }
            }
        }
    }
}

// ---------------------------------------------------------------------------
// Kernel 3: causal flash attention with f16 MFMA (verified round 3);
// only change: epilogue writes y as f16 so the out-GEMM A-operand is ready.
// ---------------------------------------------------------------------------
__global__ __launch_bounds__(256)
void attn_kernel(const float* __restrict__ qb, const _Float16* __restrict__ k16,
                 const _Float16* __restrict__ v16t, _Float16* __restrict__ y16) {
    __shared__ _Float16 Klds[64 * 64];     // [key][d], swizzled
    __shared__ _Float16 Vlds[64 * 64];     // [d][key], swizzled
    __shared__ _Float16 Plds[4 * 16 * 64]; // per-wave [kg(8)][q(16)][8]

    const int tid  = threadIdx.x;
    const int w    = tid >> 6;
    const int lane = tid & 63;
    const int lq   = lane & 15;
    const int lg   = lane >> 4;

    const int bid = blockIdx.x;
    const int h   = ((bid & 7) << 1) | ((bid >> 3) & 1);  // head -> XCD affinity
    const int qt  = (NQT - 1) - (bid >> 4);               // heavy q-tiles first
    const int q0  = qt * 64;

    const float*    qh = qb   + (size_t)h * T_SEQ * HD;
    const _Float16* kh = k16  + (size_t)h * T_SEQ * HD;
    const _Float16* vh = v16t + (size_t)h * HD * T_SEQ;

    const int qrow = q0 + w * 16 + lq;
    f16x8 qf[2];
#pragma unroll
    for (int ks = 0; ks < 2; ++ks) {
        float4 a = *(const float4*)(qh + (size_t)qrow * HD + lg * 8 + ks * 32);
        float4 b = *(const float4*)(qh + (size_t)qrow * HD + lg * 8 + ks * 32 + 4);
        f16x8 t = {(_Float16)(a.x * 0.125f), (_Float16)(a.y * 0.125f),
                   (_Float16)(a.z * 0.125f), (_Float16)(a.w * 0.125f),
                   (_Float16)(b.x * 0.125f), (_Float16)(b.y * 0.125f),
                   (_Float16)(b.z * 0.125f), (_Float16)(b.w * 0.125f)};
        qf[ks] = t;
    }

    const int srow = tid >> 4;
    const int scol = (tid & 15) * 4;
    const int schk = (tid & 15) >> 1;
    const int ssub = (tid & 1) * 8;

    float m_r = -3e38f, l_r = 0.f;
    f32x4 acco[4] = {};

    _Float16* Pw = Plds + w * 1024;

    for (int kt = 0; kt <= qt; ++kt) {
        const int k0 = kt * 64;
        f16x4 kreg[4], vreg[4];
#pragma unroll
        for (int it = 0; it < 4; ++it) {
            int row = srow + it * 16;
            kreg[it] = *(const f16x4*)(kh + (size_t)(k0 + row) * HD + scol);
            vreg[it] = *(const f16x4*)(vh + (size_t)row * T_SEQ + k0 + scol);
        }
        __syncthreads();
#pragma unroll
        for (int it = 0; it < 4; ++it) {
            int row = srow + it * 16;
            int chunk = schk ^ (row & 7);
            *(f16x4*)((char*)Klds + row * 128 + chunk * 16 + ssub) = kreg[it];
            *(f16x4*)((char*)Vlds + row * 128 + chunk * 16 + ssub) = vreg[it];
        }
        __syncthreads();

        f32x4 s[4] = {};
#pragma unroll
        for (int mb = 0; mb < 4; ++mb) {
            int row = mb * 16 + lq;
#pragma unroll
            for (int ks = 0; ks < 2; ++ks) {
                f16x8 kf = *(const f16x8*)((char*)Klds + row * 128 +
                                           (((lg + 4 * ks) ^ (lq & 7)) * 16));
                s[mb] = __builtin_amdgcn_mfma_f32_16x16x32_f16(kf, qf[ks], s[mb], 0, 0, 0);
            }
        }
        if (kt == qt) {
            const int qloc = w * 16 + lq;
#pragma unroll
            for (int mb = 0; mb < 4; ++mb)
#pragma unroll
                for (int r = 0; r < 4; ++r)
                    if (mb * 16 + lg * 4 + r > qloc) s[mb][r] = -3e38f;
        }

        float tmax = s[0][0];
#pragma unroll
        for (int mb = 0; mb < 4; ++mb)
#pragma unroll
            for (int r = 0; r < 4; ++r) tmax = fmaxf(tmax, s[mb][r]);
        tmax = fmaxf(tmax, __shfl_xor(tmax, 16));
        tmax = fmaxf(tmax, __shfl_xor(tmax, 32));
        float mn  = fmaxf(m_r, tmax);
        float scl = __expf(m_r - mn);
        m_r = mn;

        float tsum = 0.f;
#pragma unroll
        for (int mb = 0; mb < 4; ++mb) {
            float p0 = __expf(s[mb][0] - mn), p1 = __expf(s[mb][1] - mn);
            float p2 = __expf(s[mb][2] - mn), p3 = __expf(s[mb][3] - mn);
            tsum += (p0 + p1) + (p2 + p3);
            f16x4 pk = {(_Float16)p0, (_Float16)p1, (_Float16)p2, (_Float16)p3};
            *(f16x4*)(Pw + (mb * 2 + (lg >> 1)) * 128 + lq * 8 + (lg & 1) * 4) = pk;
        }
        tsum += __shfl_xor(tsum, 16);
        tsum += __shfl_xor(tsum, 32);
        l_r = l_r * scl + tsum;
#pragma unroll
        for (int mb = 0; mb < 4; ++mb)
#pragma unroll
            for (int r = 0; r < 4; ++r) acco[mb][r] *= scl;

        f16x8 pf[2];
#pragma unroll
        for (int ks = 0; ks < 2; ++ks)
            pf[ks] = *(const f16x8*)(Pw + (lg + 4 * ks) * 128 + lq * 8);
#pragma unroll
        for (int mb = 0; mb < 4; ++mb) {
            int row = mb * 16 + lq;
#pragma unroll
            for (int ks = 0; ks < 2; ++ks) {
                f16x8 vf = *(const f16x8*)((char*)Vlds + row * 128 +
                                           (((lg + 4 * ks) ^ (lq & 7)) * 16));
                acco[mb] = __builtin_amdgcn_mfma_f32_16x16x32_f16(vf, pf[ks], acco[mb], 0, 0, 0);
            }
        }
    }

    float inv = 1.f / l_r;
#pragma unroll
    for (int mb = 0; mb < 4; ++mb) {
        f16x4 o = {(_Float16)(acco[mb][0] * inv), (_Float16)(acco[mb][1] * inv),
                   (_Float16)(acco[mb][2] * inv), (_Float16)(acco[mb][3] * inv)};
        *(f16x4*)(y16 + (size_t)qrow * DMODEL + h * HD + mb * 16 + lg * 4) = o;
    }
}

// ---------------------------------------------------------------------------
extern "C" void kernel_launch(void* const* d_in, const int* in_sizes, int n_in,
                              void* d_out, int out_size, void* d_ws, size_t ws_size,
                              hipStream_t stream) {
    const float* x     = (const float*)d_in[0];
    const float* W_in  = (const float*)d_in[1];
    const float* b_in  = (const float*)d_in[2];
    const float* W_out = (const float*)d_in[3];
    const float* b_out = (const float*)d_in[4];
    float* out = (float*)d_out;

    float* ws = (float*)d_ws;
    float* q_ws = ws;                         // [h][t][64] f32
    float* k_ws = ws + HTD;                   // [h][t][64] f32
    float* tab  = ws + 2 * HTD;               // [t][64] sin|cos (262144 f32)
    _Float16* f16b = (_Float16*)(ws + 2 * HTD + (size_t)T_SEQ * 64);
    _Float16* k16  = f16b;                    // [h][t][64]
    _Float16* v16t = k16 + HTD;               // [h][d][t]
    _Float16* x16  = v16t + HTD;              // [t][1024]
    _Float16* y16  = x16;                     // alias: attn writes after proj reads
    _Float16* wi16 = x16 + (size_t)T_SEQ * DMODEL;       // [3072][1024]
    _Float16* wo16 = wi16 + (size_t)3072 * DMODEL;       // [1024][1024]

    // 0) sin/cos table + f16 casts
    sincos_table_kernel<<<(T_SEQ * 32 + 255) / 256, 256, 0, stream>>>(tab);
    cast3_kernel<<<4096, 256, 0, stream>>>(x, W_in, W_out, x16, wi16, wo16);

    // 1) proj GEMM (f16 MFMA): q,k f32 + v16t
    gemm16_kernel<1><<<768, 256, 0, stream>>>(
        x16, wi16, b_in, q_ws, v16t, T_SEQ, 3072, DMODEL, 24);

    // 2) RoPE: q in-place f32, k -> k16
    rope_kernel<<<(2 * NH * T_SEQ * 32) / 256, 256, 0, stream>>>(q_ws, k_ws, k16, tab);

    // 3) causal flash attention -> y16 [t][h*64+d] f16
    attn_kernel<<<NQT * NH, 256, 0, stream>>>(q_ws, k16, v16t, y16);

    // 4) out GEMM (f16 MFMA) -> fp32 out
    gemm16_kernel<0><<<256, 256, 0, stream>>>(
        y16, wo16, b_out, out, nullptr, T_SEQ, DMODEL, DMODEL, 8);
}

// Round 6
// 237.085 us; speedup vs baseline: 5.4195x; 1.0076x over previous
//
#include <hip/hip_runtime.h>
#include <math.h>

// Problem constants (B=1)
#define T_SEQ 4096
#define DMODEL 1024
#define NH 16
#define HD 64           // KD = VD = 64
#define NQT (T_SEQ / 64)

typedef _Float16 f16x4 __attribute__((ext_vector_type(4)));
typedef _Float16 f16x8 __attribute__((ext_vector_type(8)));
typedef float f32x4 __attribute__((ext_vector_type(4)));

#define HTD ((size_t)NH * T_SEQ * HD)   // 4,194,304

// ---------------------------------------------------------------------------
// Kernel 0: sin/cos table [t][ sin(32) | cos(32) ]
// ---------------------------------------------------------------------------
__global__ __launch_bounds__(256)
void sincos_table_kernel(float* __restrict__ tab) {
    int idx = blockIdx.x * 256 + threadIdx.x;
    if (idx >= T_SEQ * 32) return;
    int t = idx >> 5, j = idx & 31;
    double p = (double)((float)j / 31.0f);
    float theta = (float)pow(10000.0, p);
    float ang = (float)t / theta;
    double a = (double)ang;
    tab[t * 64 + j]      = (float)sin(a);
    tab[t * 64 + 32 + j] = (float)cos(a);
}

// ---------------------------------------------------------------------------
// Kernel 0.5: cast x, W_in, W_out to f16 (vec8).
// ---------------------------------------------------------------------------
__global__ __launch_bounds__(256)
void cast3_kernel(const float* __restrict__ x, const float* __restrict__ wi,
                  const float* __restrict__ wo, _Float16* __restrict__ x16,
                  _Float16* __restrict__ wi16, _Float16* __restrict__ wo16) {
    size_t gid = (size_t)blockIdx.x * 256 + threadIdx.x;   // 1,048,576 total
    const float* src; _Float16* dst; size_t i;
    if (gid < 524288)       { src = x;  dst = x16;  i = gid; }
    else if (gid < 917504)  { src = wi; dst = wi16; i = gid - 524288; }
    else                    { src = wo; dst = wo16; i = gid - 917504; }
    float4 a = *((const float4*)src + i * 2);
    float4 b = *((const float4*)src + i * 2 + 1);
    f16x8 o = {(_Float16)a.x, (_Float16)a.y, (_Float16)a.z, (_Float16)a.w,
               (_Float16)b.x, (_Float16)b.y, (_Float16)b.z, (_Float16)b.w};
    *((f16x8*)dst + i) = o;
}

// ---------------------------------------------------------------------------
// Kernel 2: RoPE in-place on f16 q16/k16 ([h][t][64]); q also scaled by 1/8.
// ---------------------------------------------------------------------------
__global__ __launch_bounds__(256)
void rope16_kernel(_Float16* __restrict__ q16, _Float16* __restrict__ k16,
                   const float* __restrict__ tab) {
    int idx = blockIdx.x * 256 + threadIdx.x;   // bits: [z:1][h:4][t:12][j:5]
    int j = idx & 31;
    int t = (idx >> 5) & (T_SEQ - 1);
    int h = (idx >> 17) & (NH - 1);
    int z = idx >> 21;                           // 0 = q, 1 = k
    float s = tab[t * 64 + j];
    float c = tab[t * 64 + 32 + j];
    _Float16* base = (z ? k16 : q16) + ((size_t)h * T_SEQ + t) * HD;
    float a = (float)base[j], b = (float)base[j + 32];
    float lo = b * c + a * s;
    float hi = a * c - b * s;
    if (z == 0) { lo *= 0.125f; hi *= 0.125f; }
    base[j]      = (_Float16)lo;
    base[j + 32] = (_Float16)hi;
}

// ---------------------------------------------------------------------------
// Kernels 1 & 4: f16 MFMA GEMM  C[M][N] = A[M][K] . B[N][K]^T + bias[N]
// 128x128 tile, BK=64, 4 waves (2x2 of 64x64), mfma_f32_16x16x32_f16.
// EPI=0: f32 out [M][N]. EPI=1: q/k f16 [h][t][64] (roped later), v f16 [h][d][t].
// ---------------------------------------------------------------------------
template<int EPI>
__global__ __launch_bounds__(256)
void gemm16_kernel(const _Float16* __restrict__ A, const _Float16* __restrict__ B,
                   const float* __restrict__ bias, float* __restrict__ out,
                   _Float16* __restrict__ outv, int M, int N, int K, int gx) {
    __shared__ _Float16 Alds[128 * 64];
    __shared__ _Float16 Blds[128 * 64];
    const int tid = threadIdx.x;
    const int w = tid >> 6, lane = tid & 63, lq = lane & 15, lg = lane >> 4;
    const int wr = w >> 1, wc = w & 1;

    // bijective XCD swizzle (gridDim.x % 8 == 0 for both call sites)
    int cpx = (int)gridDim.x >> 3;
    int tileid = (blockIdx.x & 7) * cpx + (blockIdx.x >> 3);
    const int bx = tileid % gx, by = tileid / gx;
    const int row0 = by * 128, col0 = bx * 128;

    const int ra = tid >> 1, ha = tid & 1;
    const _Float16* Ap = A + (size_t)(row0 + ra) * K + ha * 32;
    const _Float16* Bp = B + (size_t)(col0 + ra) * K + ha * 32;
    char* Awr = (char*)Alds + ra * 128;
    char* Bwr = (char*)Blds + ra * 128;
    int wsw[4];
#pragma unroll
    for (int j = 0; j < 4; ++j) wsw[j] = ((ha * 4 + j) ^ (ra & 7)) * 16;

    f32x4 acc[4][4] = {};
    f16x8 sa[4], sb[4];
#pragma unroll
    for (int j = 0; j < 4; ++j) {
        sa[j] = *(const f16x8*)(Ap + j * 8);
        sb[j] = *(const f16x8*)(Bp + j * 8);
    }

    const int nkt = K >> 6;
    for (int kt = 0; kt < nkt; ++kt) {
        __syncthreads();   // previous compute done reading LDS
#pragma unroll
        for (int j = 0; j < 4; ++j) {
            *(f16x8*)(Awr + wsw[j]) = sa[j];
            *(f16x8*)(Bwr + wsw[j]) = sb[j];
        }
        __syncthreads();   // staged
        if (kt + 1 < nkt) {
            int kn = (kt + 1) << 6;
#pragma unroll
            for (int j = 0; j < 4; ++j) {
                sa[j] = *(const f16x8*)(Ap + kn + j * 8);
                sb[j] = *(const f16x8*)(Bp + kn + j * 8);
            }
        }
#pragma unroll
        for (int ks = 0; ks < 2; ++ks) {
            f16x8 af[4], bf[4];
            const int cofs = ((ks * 4 + lg) ^ (lq & 7)) * 16;
#pragma unroll
            for (int i = 0; i < 4; ++i) {
                int rA = wr * 64 + i * 16 + lq;
                int rB = wc * 64 + i * 16 + lq;
                af[i] = *(const f16x8*)((char*)Alds + rA * 128 + cofs);
                bf[i] = *(const f16x8*)((char*)Blds + rB * 128 + cofs);
            }
#pragma unroll
            for (int mi = 0; mi < 4; ++mi)
#pragma unroll
                for (int nj = 0; nj < 4; ++nj)
                    acc[mi][nj] = __builtin_amdgcn_mfma_f32_16x16x32_f16(
                        af[mi], bf[nj], acc[mi][nj], 0, 0, 0);
        }
    }

    // epilogue. D-layout: C[row0+wr*64+mi*16+lg*4+r][col0+wc*64+nj*16+lq]
    if (EPI == 0) {
#pragma unroll
        for (int nj = 0; nj < 4; ++nj) {
            int n = col0 + wc * 64 + nj * 16 + lq;
            float bv = bias[n];
#pragma unroll
            for (int mi = 0; mi < 4; ++mi) {
                int t0 = row0 + wr * 64 + mi * 16 + lg * 4;
#pragma unroll
                for (int r = 0; r < 4; ++r)
                    out[(size_t)(t0 + r) * N + n] = acc[mi][nj][r] + bv;
            }
        }
    } else {
        const int tensor = col0 >> 10;            // 0=q, 1=k, 2=v (no straddle)
        const int m0b = row0 + wr * 64;
        if (tensor == 2) {
            // v: f16 transposed [h][d][t], f16x4 along t
#pragma unroll
            for (int nj = 0; nj < 4; ++nj) {
                int n = col0 + wc * 64 + nj * 16 + lq;
                int nn = n & 1023; int hh = nn >> 6, d = nn & 63;
                float bv = bias[n];
                _Float16* dv = outv + 2 * HTD + (size_t)(hh * 64 + d) * T_SEQ;
#pragma unroll
                for (int mi = 0; mi < 4; ++mi) {
                    int t0 = m0b + mi * 16 + lg * 4;
                    f16x4 val = {(_Float16)(acc[mi][nj][0] + bv),
                                 (_Float16)(acc[mi][nj][1] + bv),
                                 (_Float16)(acc[mi][nj][2] + bv),
                                 (_Float16)(acc[mi][nj][3] + bv)};
                    *(f16x4*)(dv + t0) = val;
                }
            }
        } else {
            // q/k: f16 [h][t][64] (RoPE applied afterwards in-place)
            _Float16* dst = outv + (size_t)tensor * HTD;
#pragma unroll
            for (int nj = 0; nj < 4; ++nj) {
                int n = col0 + wc * 64 + nj * 16 + lq;
                int nn = n & 1023; int hh = nn >> 6, d = nn & 63;
                float bv = bias[n];
                _Float16* dcol = dst + (size_t)hh * T_SEQ * HD + d;
#pragma unroll
                for (int mi = 0; mi < 4; ++mi) {
                    int t0 = m0b + mi * 16 + lg * 4;
#pragma unroll
                    for (int r = 0; r < 4; ++r)
                        dcol[(size_t)(t0 + r) * HD] = (_Float16)(acc[mi][nj][r] + bv);
                }
            }
        }
    }
}

// ---------------------------------------------------------------------------
// Kernel 3: causal flash attention, f16 MFMA 16x16x32 (verified layout).
// Changes vs round 4: q loaded as pre-roped/scaled f16 fragments; double-
// buffered K/V LDS with one barrier per tile and next-tile prefetch into
// registers; q-tile pairing (block does tiles 63-p and p -> equal work);
// defer-max (skip rescale unless max grew > 8); setprio around MFMA clusters.
// ---------------------------------------------------------------------------
__global__ __launch_bounds__(256)
void attn_kernel(const _Float16* __restrict__ q16, const _Float16* __restrict__ k16,
                 const _Float16* __restrict__ v16t, _Float16* __restrict__ y16) {
    __shared__ _Float16 Klds[2][64 * 64];  // [key][d], swizzled
    __shared__ _Float16 Vlds[2][64 * 64];  // [d][key], swizzled
    __shared__ _Float16 Plds[4 * 16 * 64]; // per-wave [kg(8)][q(16)][8]

    const int tid  = threadIdx.x;
    const int w    = tid >> 6;
    const int lane = tid & 63;
    const int lq   = lane & 15;
    const int lg   = lane >> 4;

    const int bid  = blockIdx.x;                          // 512 blocks
    const int h    = ((bid & 7) << 1) | ((bid >> 3) & 1); // head -> XCD affinity
    const int pr   = bid >> 4;                            // 0..31 pair index

    const _Float16* qh = q16  + (size_t)h * T_SEQ * HD;
    const _Float16* kh = k16  + (size_t)h * T_SEQ * HD;
    const _Float16* vh = v16t + (size_t)h * HD * T_SEQ;

    const int srow = tid >> 4;           // staging row (+16 per it)
    const int scol = (tid & 15) * 4;     // staging f16 col
    const int schk = (tid & 15) >> 1;    // 16B chunk within row
    const int ssub = (tid & 1) * 8;      // byte offset within chunk

    _Float16* Pw = Plds + w * 1024;

    for (int half = 0; half < 2; ++half) {
        const int qt = half ? pr : (NQT - 1 - pr);   // heavy tile first
        const int q0 = qt * 64;
        const int qrow = q0 + w * 16 + lq;

        f16x8 qf[2];
        qf[0] = *(const f16x8*)(qh + (size_t)qrow * HD + lg * 8);
        qf[1] = *(const f16x8*)(qh + (size_t)qrow * HD + lg * 8 + 32);

        float m_r = -3e38f, l_r = 0.f;
        f32x4 acco[4] = {};

        // prologue: load tile 0 and stage into buffer 0
        f16x4 kreg[4], vreg[4];
#pragma unroll
        for (int it = 0; it < 4; ++it) {
            int row = srow + it * 16;
            kreg[it] = *(const f16x4*)(kh + (size_t)row * HD + scol);
            vreg[it] = *(const f16x4*)(vh + (size_t)row * T_SEQ + scol);
        }
        __syncthreads();   // all waves done with previous half's buffers
#pragma unroll
        for (int it = 0; it < 4; ++it) {
            int row = srow + it * 16;
            int chunk = schk ^ (row & 7);
            *(f16x4*)((char*)Klds[0] + row * 128 + chunk * 16 + ssub) = kreg[it];
            *(f16x4*)((char*)Vlds[0] + row * 128 + chunk * 16 + ssub) = vreg[it];
        }

        int cur = 0;
        for (int kt = 0; kt <= qt; ++kt) {
            __syncthreads();   // buf[cur] staged by all; prev compute done
            if (kt < qt) {     // prefetch next tile (latency hides under compute)
                const int k0n = (kt + 1) * 64;
#pragma unroll
                for (int it = 0; it < 4; ++it) {
                    int row = srow + it * 16;
                    kreg[it] = *(const f16x4*)(kh + (size_t)(k0n + row) * HD + scol);
                    vreg[it] = *(const f16x4*)(vh + (size_t)row * T_SEQ + k0n + scol);
                }
            }

            // QK^T: S^T[key][q]
            f32x4 s[4] = {};
            __builtin_amdgcn_s_setprio(1);
#pragma unroll
            for (int mb = 0; mb < 4; ++mb) {
                int row = mb * 16 + lq;
#pragma unroll
                for (int ks = 0; ks < 2; ++ks) {
                    f16x8 kf = *(const f16x8*)((char*)Klds[cur] + row * 128 +
                                               (((lg + 4 * ks) ^ (lq & 7)) * 16));
                    s[mb] = __builtin_amdgcn_mfma_f32_16x16x32_f16(kf, qf[ks], s[mb], 0, 0, 0);
                }
            }
            __builtin_amdgcn_s_setprio(0);
            if (kt == qt) {   // causal mask on diagonal tile
                const int qloc = w * 16 + lq;
#pragma unroll
                for (int mb = 0; mb < 4; ++mb)
#pragma unroll
                    for (int r = 0; r < 4; ++r)
                        if (mb * 16 + lg * 4 + r > qloc) s[mb][r] = -3e38f;
            }

            // online softmax with defer-max (per-lane q = lq)
            float tmax = s[0][0];
#pragma unroll
            for (int mb = 0; mb < 4; ++mb)
#pragma unroll
                for (int r = 0; r < 4; ++r) tmax = fmaxf(tmax, s[mb][r]);
            tmax = fmaxf(tmax, __shfl_xor(tmax, 16));
            tmax = fmaxf(tmax, __shfl_xor(tmax, 32));
            if (__ballot(tmax > m_r + 8.0f)) {   // rescale only on real growth
                float mn  = fmaxf(m_r, tmax);
                float scl = __expf(m_r - mn);
                m_r = mn;
                l_r *= scl;
#pragma unroll
                for (int mb = 0; mb < 4; ++mb)
#pragma unroll
                    for (int r = 0; r < 4; ++r) acco[mb][r] *= scl;
            }

            float tsum = 0.f;
#pragma unroll
            for (int mb = 0; mb < 4; ++mb) {
                float p0 = __expf(s[mb][0] - m_r), p1 = __expf(s[mb][1] - m_r);
                float p2 = __expf(s[mb][2] - m_r), p3 = __expf(s[mb][3] - m_r);
                tsum += (p0 + p1) + (p2 + p3);
                f16x4 pk = {(_Float16)p0, (_Float16)p1, (_Float16)p2, (_Float16)p3};
                *(f16x4*)(Pw + (mb * 2 + (lg >> 1)) * 128 + lq * 8 + (lg & 1) * 4) = pk;
            }
            tsum += __shfl_xor(tsum, 16);
            tsum += __shfl_xor(tsum, 32);
            l_r += tsum;

            // PV: O^T[d][q] += V^T[d][key] . P^T[key][q]
            f16x8 pf[2];
#pragma unroll
            for (int ks = 0; ks < 2; ++ks)
                pf[ks] = *(const f16x8*)(Pw + (lg + 4 * ks) * 128 + lq * 8);
            __builtin_amdgcn_s_setprio(1);
#pragma unroll
            for (int mb = 0; mb < 4; ++mb) {
                int row = mb * 16 + lq;
#pragma unroll
                for (int ks = 0; ks < 2; ++ks) {
                    f16x8 vf = *(const f16x8*)((char*)Vlds[cur] + row * 128 +
                                               (((lg + 4 * ks) ^ (lq & 7)) * 16));
                    acco[mb] = __builtin_amdgcn_mfma_f32_16x16x32_f16(vf, pf[ks], acco[mb], 0, 0, 0);
                }
            }
            __builtin_amdgcn_s_setprio(0);

            if (kt < qt) {   // stage prefetched tile into the other buffer
#pragma unroll
                for (int it = 0; it < 4; ++it) {
                    int row = srow + it * 16;
                    int chunk = schk ^ (row & 7);
                    *(f16x4*)((char*)Klds[cur ^ 1] + row * 128 + chunk * 16 + ssub) = kreg[it];
                    *(f16x4*)((char*)Vlds[cur ^ 1] + row * 128 + chunk * 16 + ssub) = vreg[it];
                }
                cur ^= 1;
            }
        }

        // epilogue: O[q][d] = O^T / l  (f16 for the out-GEMM A-operand)
        float inv = 1.f / l_r;
#pragma unroll
        for (int mb = 0; mb < 4; ++mb) {
            f16x4 o = {(_Float16)(acco[mb][0] * inv), (_Float16)(acco[mb][1] * inv),
                       (_Float16)(acco[mb][2] * inv), (_Float16)(acco[mb][3] * inv)};
            *(f16x4*)(y16 + (size_t)qrow * DMODEL + h * HD + mb * 16 + lg * 4) = o;
        }
    }
}

// ---------------------------------------------------------------------------
extern "C" void kernel_launch(void* const* d_in, const int* in_sizes, int n_in,
                              void* d_out, int out_size, void* d_ws, size_t ws_size,
                              hipStream_t stream) {
    const float* x     = (const float*)d_in[0];
    const float* W_in  = (const float*)d_in[1];
    const float* b_in  = (const float*)d_in[2];
    const float* W_out = (const float*)d_in[3];
    const float* b_out = (const float*)d_in[4];
    float* out = (float*)d_out;

    float* ws = (float*)d_ws;
    float* tab = ws;                              // [t][64] sin|cos (262144 f32)
    _Float16* fb   = (_Float16*)(ws + (size_t)T_SEQ * 64);
    _Float16* q16  = fb;                          // [h][t][64]
    _Float16* k16  = fb + HTD;                    // [h][t][64]
    _Float16* v16t = fb + 2 * HTD;                // [h][d][t]
    _Float16* x16  = fb + 3 * HTD;                // [t][1024]
    _Float16* y16  = x16;                         // alias: attn writes after proj reads
    _Float16* wi16 = x16 + (size_t)T_SEQ * DMODEL;     // [3072][1024]
    _Float16* wo16 = wi16 + (size_t)3072 * DMODEL;     // [1024][1024]

    // 0) sin/cos table + f16 casts
    sincos_table_kernel<<<(T_SEQ * 32 + 255) / 256, 256, 0, stream>>>(tab);
    cast3_kernel<<<4096, 256, 0, stream>>>(x, W_in, W_out, x16, wi16, wo16);

    // 1) proj GEMM (f16 MFMA): q16, k16 (unroped), v16t
    gemm16_kernel<1><<<768, 256, 0, stream>>>(
        x16, wi16, b_in, nullptr, q16, T_SEQ, 3072, DMODEL, 24);

    // 2) RoPE in-place on q16 (+1/8 scale) and k16
    rope16_kernel<<<(2 * NH * T_SEQ * 32) / 256, 256, 0, stream>>>(q16, k16, tab);

    // 3) causal flash attention -> y16 [t][h*64+d] f16 (paired q-tiles)
    attn_kernel<<<512, 256, 0, stream>>>(q16, k16, v16t, y16);

    // 4) out GEMM (f16 MFMA) -> fp32 out
    gemm16_kernel<0><<<256, 256, 0, stream>>>(
        y16, wo16, b_out, out, nullptr, T_SEQ, DMODEL, DMODEL, 8);
}